// Round 2
// baseline (11620.906 us; speedup 1.0000x reference)
//
#include <hip/hip_runtime.h>
#include <hip/hip_cooperative_groups.h>
#include <math.h>

namespace cg = cooperative_groups;

#define EOS_TOK 1
#define SOS_TOK 2

#define Bn 32
#define Hn 512
#define En 256
#define Vn 32000
#define G3H 1536                 // 3*H
#define NROWS (Vn + G3H)         // 33536 = 131 * 256
#define NBLK 256                 // 1 block/CU -> cooperative co-residency always satisfiable
#define NTHR 256
#define VT 8
#define RPB (NROWS / NBLK)       // 131 rows per block (exact)
#define GHPB (G3H / NBLK)        // 6 gh rows per block in the pre-pass

typedef unsigned long long ull;

// 64 KB exactly. Phase-B h-tile, phase-B argmax scratch (aliased after h is dead),
// and phase-A scratch (aliased; phases separated by barriers / grid.sync).
union SMem {
    float4 h[Bn * (Hn / 4)];                 // 4096 float4, XOR-swizzled
    ull red[8 * Bn];                          // aliases h[0..511] AFTER all h reads
    struct { int tok[Bn]; float gx[2][3][Bn]; } a;
};

__device__ __forceinline__ unsigned int fkey(float f) {
    // order-preserving fp32 -> u32 (monotone for non-NaN)
    unsigned int b = __float_as_uint(f);
    return (b & 0x80000000u) ? ~b : (b | 0x80000000u);
}

// ---------------- Phase B: logits over V rows + next-step gh rows, partial argmax ----
__device__ __forceinline__ void phase_b(
    int tid, int bid, int first, int t,
    const float* __restrict__ W_proj, const float* __restrict__ W_hh,
    const float* __restrict__ b_proj, const float* __restrict__ b_hh,
    const float* __restrict__ ws_h, float* __restrict__ ws_gh,
    ull* __restrict__ slots, SMem* sm)
{
    // stage h (B x H) into swizzled LDS: logical (b,e4) -> phys b*128 + (e4 ^ (b&7))
    const float4* hsrc = (const float4*)ws_h;
    for (int i = tid; i < Bn * (Hn / 4); i += NTHR) {
        int b  = i >> 7;
        int e4 = i & 127;
        sm->h[(b << 7) + (e4 ^ (b & 7))] = hsrc[i];
    }
    __syncthreads();

    int rs, re;
    if (first) { rs = Vn + bid * GHPB; re = rs + GHPB; }
    else       { rs = bid * RPB;       re = rs + RPB;  }

    const int g  = tid >> 5;        // row group 0..7
    const int b  = tid & 31;        // batch lane
    const int sw = b & 7;           // swizzle constant
    const float4* hrow = sm->h + (b << 7);
    ull bestPack = 0ull;

    for (int r0 = rs + g * VT; r0 < re; r0 += 8 * VT) {
        const int nv = re - r0;     // valid rows this tile (>=1)
        const float* wr[VT];
        #pragma unroll
        for (int i = 0; i < VT; ++i) {
            int r = (i < nv) ? (r0 + i) : r0;   // clamp OOB to a valid row; result unused
            wr[i] = (r < Vn) ? (W_proj + (size_t)r * Hn)
                             : (W_hh   + (size_t)(r - Vn) * Hn);
        }
        float accx[VT], accy[VT];
        #pragma unroll
        for (int i = 0; i < VT; ++i) { accx[i] = 0.f; accy[i] = 0.f; }

        for (int e4 = 0; e4 < Hn / 4; ++e4) {
            float4 h4 = hrow[e4 ^ sw];
            #pragma unroll
            for (int i = 0; i < VT; ++i) {
                float4 w4 = *(const float4*)(wr[i] + 4 * e4);
                accx[i] = fmaf(h4.x, w4.x, accx[i]);
                accy[i] = fmaf(h4.y, w4.y, accy[i]);
                accx[i] = fmaf(h4.z, w4.z, accx[i]);
                accy[i] = fmaf(h4.w, w4.w, accy[i]);
            }
        }
        #pragma unroll
        for (int i = 0; i < VT; ++i) {
            if (i < nv) {
                int r = r0 + i;
                float v = accx[i] + accy[i];
                if (r < Vn) {
                    v += b_proj[r];
                    ull pk = ((ull)fkey(v) << 32) | (unsigned int)(~(unsigned int)r);
                    if (pk > bestPack) bestPack = pk;   // ties: smaller r wins via ~r
                } else {
                    ws_gh[(size_t)b * G3H + (r - Vn)] = v + b_hh[r - Vn];
                }
            }
        }
    }

    if (!first) {
        __syncthreads();                       // all h reads complete before aliasing
        sm->red[(g << 5) + b] = bestPack;
        __syncthreads();
        if (tid < Bn) {
            ull m = sm->red[tid];
            #pragma unroll
            for (int s = 1; s < 8; ++s) {
                ull v = sm->red[(s << 5) + tid];
                if (v > m) m = v;
            }
            if (m != 0ull)
                atomicMax(&slots[((size_t)(t & 1) * 8 + (bid & 7)) * Bn + tid], m);
        }
    }
}

// ---------------- Phase A: token resolve + embed/gx + gate combine + h update -------
__device__ __forceinline__ void phase_a(
    int tid, int bid, int t, int T,
    const float* __restrict__ emb, const float* __restrict__ W_ih,
    const float* __restrict__ b_ih,
    float* __restrict__ ws_h, const float* __restrict__ ws_gh,
    ull* __restrict__ slots, int* __restrict__ done,
    int* __restrict__ out, SMem* sm)
{
    if (tid < Bn) {
        int b = tid;
        int tok, dnew;
        if (t == 0) { tok = SOS_TOK; dnew = 0; }
        else {
            const ull* sl = slots + (size_t)((t - 1) & 1) * (8 * Bn);
            ull m = sl[b];
            #pragma unroll
            for (int s = 1; s < 8; ++s) {
                ull v = sl[s * Bn + b];
                if (v > m) m = v;
            }
            int idx = (int)(~(unsigned int)m);
            int dold = done[((t - 1) & 1) * Bn + b];
            tok  = dold ? EOS_TOK : idx;
            dnew = dold | (idx == EOS_TOK);
        }
        sm->a.tok[b] = tok;
        if (bid == 0) {
            done[(t & 1) * Bn + b] = dnew;
            if (t > 0) out[(size_t)(t - 1) * Bn + b] = tok;
            ull* sr = slots + (size_t)(t & 1) * (8 * Bn);   // reset parity (t&1) for B(t)
            #pragma unroll
            for (int s = 0; s < 8; ++s) sr[s * Bn + b] = 0ull;
        }
    }
    __syncthreads();
    if (t >= T) return;          // tail call: resolve only (uniform branch)

    // gx dots: block bid owns columns {bid, bid+256}; 192 dots of length E.
    if (tid < 192) {
        int b    = tid & 31;
        int rem  = tid >> 5;     // 0..5
        int gate = rem >> 1;
        int ci   = rem & 1;
        int col  = bid + (ci << 8);
        const float* wrow = W_ih + (size_t)(gate * Hn + col) * En;
        const float* xrow = emb + (size_t)sm->a.tok[b] * En;
        float ax = 0.f, ay = 0.f;
        #pragma unroll 8
        for (int e4 = 0; e4 < En / 4; ++e4) {
            float4 w4 = *(const float4*)(wrow + 4 * e4);
            float4 x4 = *(const float4*)(xrow + 4 * e4);
            ax = fmaf(x4.x, w4.x, ax);
            ay = fmaf(x4.y, w4.y, ay);
            ax = fmaf(x4.z, w4.z, ax);
            ay = fmaf(x4.w, w4.w, ay);
        }
        sm->a.gx[ci][gate][b] = ax + ay;
    }
    __syncthreads();

    if (tid < 64) {
        int b   = tid & 31;
        int ci  = tid >> 5;
        int col = bid + (ci << 8);
        float gxr = sm->a.gx[ci][0][b] + b_ih[col];
        float gxz = sm->a.gx[ci][1][b] + b_ih[Hn + col];
        float gxn = sm->a.gx[ci][2][b] + b_ih[2 * Hn + col];
        const float* ghrow = ws_gh + (size_t)b * G3H;      // includes b_hh already
        float ghr = ghrow[col];
        float ghz = ghrow[Hn + col];
        float ghn = ghrow[2 * Hn + col];
        float r = 1.0f / (1.0f + expf(-(gxr + ghr)));
        float z = 1.0f / (1.0f + expf(-(gxz + ghz)));
        float n = tanhf(gxn + r * ghn);
        float* hp = ws_h + (size_t)b * Hn + col;
        *hp = (1.0f - z) * n + z * (*hp);
    }
}

// ================= cooperative single-kernel path =================
__global__ void __launch_bounds__(NTHR)
decode_coop(const float* __restrict__ hidden, const float* __restrict__ emb,
            const float* __restrict__ W_ih, const float* __restrict__ W_hh,
            const float* __restrict__ b_ih, const float* __restrict__ b_hh,
            const float* __restrict__ W_proj, const float* __restrict__ b_proj,
            const int* __restrict__ max_len_p, int* __restrict__ out, void* ws_raw)
{
    cg::grid_group grid = cg::this_grid();
    const int tid = threadIdx.x, bid = blockIdx.x;
    __shared__ SMem sm;

    float* ws_h  = (float*)ws_raw;                         // [B*H]
    float* ws_gh = ws_h + Bn * Hn;                         // [B*3H]
    ull*   slots = (ull*)(ws_gh + Bn * G3H);               // [2][8][B]
    int*   done  = (int*)(slots + 2 * 8 * Bn);             // [2][B]

    const int T = max_len_p[0];

    for (int i = bid * NTHR + tid; i < Bn * Hn / 4; i += NBLK * NTHR)
        ((float4*)ws_h)[i] = ((const float4*)hidden)[i];
    grid.sync();

    phase_b(tid, bid, 1, 0, W_proj, W_hh, b_proj, b_hh, ws_h, ws_gh, slots, &sm);
    grid.sync();

    for (int t = 0; t < T; ++t) {
        phase_a(tid, bid, t, T, emb, W_ih, b_ih, ws_h, ws_gh, slots, done, out, &sm);
        grid.sync();
        phase_b(tid, bid, 0, t, W_proj, W_hh, b_proj, b_hh, ws_h, ws_gh, slots, &sm);
        grid.sync();
    }
    phase_a(tid, bid, T, T, emb, W_ih, b_ih, ws_h, ws_gh, slots, done, out, &sm);
}

// ================= non-cooperative fallback path =================
__global__ void __launch_bounds__(NTHR)
k_init(const float* __restrict__ hidden, float* __restrict__ ws_h) {
    int i = blockIdx.x * NTHR + threadIdx.x;
    if (i < Bn * Hn / 4) ((float4*)ws_h)[i] = ((const float4*)hidden)[i];
}

__global__ void __launch_bounds__(NTHR)
k_b(int first, int t, const int* __restrict__ max_len_p,
    const float* __restrict__ W_proj, const float* __restrict__ W_hh,
    const float* __restrict__ b_proj, const float* __restrict__ b_hh,
    const float* __restrict__ ws_h, float* __restrict__ ws_gh,
    ull* __restrict__ slots)
{
    if (!first && t >= max_len_p[0]) return;
    __shared__ SMem sm;
    phase_b(threadIdx.x, blockIdx.x, first, t, W_proj, W_hh, b_proj, b_hh,
            ws_h, ws_gh, slots, &sm);
}

__global__ void __launch_bounds__(NTHR)
k_a(int t, const int* __restrict__ max_len_p,
    const float* __restrict__ emb, const float* __restrict__ W_ih,
    const float* __restrict__ b_ih,
    float* __restrict__ ws_h, const float* __restrict__ ws_gh,
    ull* __restrict__ slots, int* __restrict__ done, int* __restrict__ out)
{
    int T = max_len_p[0];
    if (t > T) return;
    __shared__ SMem sm;
    phase_a(threadIdx.x, blockIdx.x, t, T, emb, W_ih, b_ih,
            ws_h, ws_gh, slots, done, out, &sm);
}

extern "C" void kernel_launch(void* const* d_in, const int* in_sizes, int n_in,
                              void* d_out, int out_size, void* d_ws, size_t ws_size,
                              hipStream_t stream) {
    const float* hidden = (const float*)d_in[0];
    const float* emb    = (const float*)d_in[1];
    const float* W_ih   = (const float*)d_in[2];
    const float* W_hh   = (const float*)d_in[3];
    const float* b_ih   = (const float*)d_in[4];
    const float* b_hh   = (const float*)d_in[5];
    const float* W_proj = (const float*)d_in[6];
    const float* b_proj = (const float*)d_in[7];
    const int* max_len  = (const int*)d_in[8];
    int* out = (int*)d_out;

    float* ws_h  = (float*)d_ws;
    float* ws_gh = ws_h + Bn * Hn;
    ull*   slots = (ull*)(ws_gh + Bn * G3H);
    int*   done  = (int*)(slots + 2 * 8 * Bn);
    void*  ws    = d_ws;

    void* args[] = {&hidden, &emb, &W_ih, &W_hh, &b_ih, &b_hh,
                    &W_proj, &b_proj, &max_len, &out, &ws};
    hipError_t err = hipLaunchCooperativeKernel((const void*)decode_coop,
                                                dim3(NBLK), dim3(NTHR), args, 0, stream);
    if (err != hipSuccess) {
        (void)hipGetLastError();   // clear sticky error; take deterministic fallback
        hipLaunchKernelGGL(k_init, dim3(16), dim3(NTHR), 0, stream, hidden, ws_h);
        hipLaunchKernelGGL(k_b, dim3(NBLK), dim3(NTHR), 0, stream,
                           1, 0, max_len, W_proj, W_hh, b_proj, b_hh, ws_h, ws_gh, slots);
        for (int t = 0; t <= 64; ++t) {
            hipLaunchKernelGGL(k_a, dim3(NBLK), dim3(NTHR), 0, stream,
                               t, max_len, emb, W_ih, b_ih, ws_h, ws_gh, slots, done, out);
            if (t < 64)
                hipLaunchKernelGGL(k_b, dim3(NBLK), dim3(NTHR), 0, stream,
                                   0, t, max_len, W_proj, W_hh, b_proj, b_hh, ws_h, ws_gh, slots);
        }
    }
}

// Round 3
// 9029.903 us; speedup vs baseline: 1.2869x; 1.2869x over previous
//
#include <hip/hip_runtime.h>
#include <hip/hip_cooperative_groups.h>
#include <math.h>

namespace cg = cooperative_groups;

#define EOS_TOK 1
#define SOS_TOK 2

#define Bn 32
#define Hn 512
#define En 256
#define Vn 32000
#define G3H 1536                 // 3*H
#define NROWS (Vn + G3H)         // 33536 = 131 * 256
#define NBLK 256                 // 1 block/CU
#define NTHR 1024                // 16 waves/block -> 4 waves/SIMD (50% occupancy)
#define GROUPS (NTHR / 32)       // 32 row groups
#define VT 4                     // rows per thread per pass; 32*4=128 rows/pass (131/block)
#define RPB (NROWS / NBLK)       // 131 rows per block (exact)
#define GHPB (G3H / NBLK)        // 6 gh rows per block in the pre-pass

typedef unsigned long long ull;

// 64 KB exactly. Phase-B h-tile; argmax scratch aliased after h reads complete;
// phase-A scratch aliased (phases separated by barriers / grid.sync).
union SMem {
    float4 h[Bn * (Hn / 4)];                  // 4096 float4, XOR-swizzled
    ull red[GROUPS * Bn];                     // 8 KB, aliases h AFTER all h reads
    struct { int tok[Bn]; float gx[2][3][Bn]; } a;
};

__device__ __forceinline__ unsigned int fkey(float f) {
    // order-preserving fp32 -> u32 (monotone for non-NaN)
    unsigned int b = __float_as_uint(f);
    return (b & 0x80000000u) ? ~b : (b | 0x80000000u);
}

// ---------------- Phase B: logits over V rows + next-step gh rows, partial argmax ----
__device__ __forceinline__ void phase_b(
    int tid, int bid, int first, int t,
    const float* __restrict__ W_proj, const float* __restrict__ W_hh,
    const float* __restrict__ b_proj, const float* __restrict__ b_hh,
    const float* __restrict__ ws_h, float* __restrict__ ws_gh,
    ull* __restrict__ slots, SMem* sm)
{
    // stage h (B x H) into swizzled LDS: logical (b,e4) -> phys b*128 + (e4 ^ (b&7))
    const float4* hsrc = (const float4*)ws_h;
    for (int i = tid; i < Bn * (Hn / 4); i += NTHR) {
        int b  = i >> 7;
        int e4 = i & 127;
        sm->h[(b << 7) + (e4 ^ (b & 7))] = hsrc[i];
    }
    __syncthreads();

    int rs, re;
    if (first) { rs = Vn + bid * GHPB; re = rs + GHPB; }
    else       { rs = bid * RPB;       re = rs + RPB;  }

    const int g  = tid >> 5;        // row group 0..31
    const int b  = tid & 31;        // batch lane
    const int sw = b & 7;           // swizzle constant
    const float4* hrow = sm->h + (b << 7);
    ull bestPack = 0ull;

    for (int r0 = rs + g * VT; r0 < re; r0 += GROUPS * VT) {
        const int nv = re - r0;     // valid rows this tile (>=1)
        const float* wr[VT];
        #pragma unroll
        for (int i = 0; i < VT; ++i) {
            int r = (i < nv) ? (r0 + i) : r0;   // clamp OOB to a valid row; result unused
            wr[i] = (r < Vn) ? (W_proj + (size_t)r * Hn)
                             : (W_hh   + (size_t)(r - Vn) * Hn);
        }
        float accx[VT], accy[VT];
        #pragma unroll
        for (int i = 0; i < VT; ++i) { accx[i] = 0.f; accy[i] = 0.f; }

        #pragma unroll 2
        for (int e4 = 0; e4 < Hn / 4; ++e4) {
            float4 h4 = hrow[e4 ^ sw];
            #pragma unroll
            for (int i = 0; i < VT; ++i) {
                float4 w4 = *(const float4*)(wr[i] + 4 * e4);
                accx[i] = fmaf(h4.x, w4.x, accx[i]);
                accy[i] = fmaf(h4.y, w4.y, accy[i]);
                accx[i] = fmaf(h4.z, w4.z, accx[i]);
                accy[i] = fmaf(h4.w, w4.w, accy[i]);
            }
        }
        #pragma unroll
        for (int i = 0; i < VT; ++i) {
            if (i < nv) {
                int r = r0 + i;
                float v = accx[i] + accy[i];
                if (r < Vn) {
                    v += b_proj[r];
                    ull pk = ((ull)fkey(v) << 32) | (unsigned int)(~(unsigned int)r);
                    if (pk > bestPack) bestPack = pk;   // ties: smaller r wins via ~r
                } else {
                    ws_gh[(size_t)b * G3H + (r - Vn)] = v + b_hh[r - Vn];
                }
            }
        }
    }

    if (!first) {
        __syncthreads();                       // all h reads complete before aliasing
        sm->red[(g << 5) + b] = bestPack;
        __syncthreads();
        if (tid < Bn) {
            ull m = sm->red[tid];
            #pragma unroll
            for (int s = 1; s < GROUPS; ++s) {
                ull v = sm->red[(s << 5) + tid];
                if (v > m) m = v;
            }
            if (m != 0ull)
                atomicMax(&slots[((size_t)(t & 1) * 8 + (bid & 7)) * Bn + tid], m);
        }
    }
}

// ---------------- Phase A: token resolve + embed/gx + gate combine + h update -------
__device__ __forceinline__ void phase_a(
    int tid, int bid, int t, int T,
    const float* __restrict__ emb, const float* __restrict__ W_ih,
    const float* __restrict__ b_ih,
    float* __restrict__ ws_h, const float* __restrict__ ws_gh,
    ull* __restrict__ slots, int* __restrict__ done,
    int* __restrict__ out, SMem* sm)
{
    if (tid < Bn) {
        int b = tid;
        int tok, dnew;
        if (t == 0) { tok = SOS_TOK; dnew = 0; }
        else {
            const ull* sl = slots + (size_t)((t - 1) & 1) * (8 * Bn);
            ull m = sl[b];
            #pragma unroll
            for (int s = 1; s < 8; ++s) {
                ull v = sl[s * Bn + b];
                if (v > m) m = v;
            }
            int idx = (int)(~(unsigned int)m);
            int dold = done[((t - 1) & 1) * Bn + b];
            tok  = dold ? EOS_TOK : idx;
            dnew = dold | (idx == EOS_TOK);
        }
        sm->a.tok[b] = tok;
        if (bid == 0) {
            done[(t & 1) * Bn + b] = dnew;
            if (t > 0) out[(size_t)(t - 1) * Bn + b] = tok;
            ull* sr = slots + (size_t)(t & 1) * (8 * Bn);   // reset parity (t&1) for B(t)
            #pragma unroll
            for (int s = 0; s < 8; ++s) sr[s * Bn + b] = 0ull;
        }
    }
    __syncthreads();
    if (t >= T) return;          // tail call: resolve only (uniform branch)

    // gx dots: block bid owns columns {bid, bid+256}; 192 dots of length E,
    // 4 threads per dot (64 elems each) -> 768 active threads.
    if (tid < 768) {
        int d    = tid >> 2;     // dot id 0..191
        int q    = tid & 3;      // quarter
        int b    = d & 31;
        int rem  = d >> 5;       // 0..5
        int gate = rem >> 1;
        int ci   = rem & 1;
        int col  = bid + (ci << 8);
        const float* wrow = W_ih + (size_t)(gate * Hn + col) * En + q * (En / 4);
        const float* xrow = emb + (size_t)sm->a.tok[b] * En + q * (En / 4);
        float ax = 0.f, ay = 0.f;
        #pragma unroll
        for (int e4 = 0; e4 < En / 16; ++e4) {     // 16 float4 iters
            float4 w4 = *(const float4*)(wrow + 4 * e4);
            float4 x4 = *(const float4*)(xrow + 4 * e4);
            ax = fmaf(x4.x, w4.x, ax);
            ay = fmaf(x4.y, w4.y, ay);
            ax = fmaf(x4.z, w4.z, ax);
            ay = fmaf(x4.w, w4.w, ay);
        }
        float a = ax + ay;
        a += __shfl_xor(a, 1);
        a += __shfl_xor(a, 2);
        if (q == 0) sm->a.gx[ci][gate][b] = a;
    }
    __syncthreads();

    if (tid < 64) {
        int b   = tid & 31;
        int ci  = tid >> 5;
        int col = bid + (ci << 8);
        float gxr = sm->a.gx[ci][0][b] + b_ih[col];
        float gxz = sm->a.gx[ci][1][b] + b_ih[Hn + col];
        float gxn = sm->a.gx[ci][2][b] + b_ih[2 * Hn + col];
        const float* ghrow = ws_gh + (size_t)b * G3H;      // includes b_hh already
        float ghr = ghrow[col];
        float ghz = ghrow[Hn + col];
        float ghn = ghrow[2 * Hn + col];
        float r = 1.0f / (1.0f + expf(-(gxr + ghr)));
        float z = 1.0f / (1.0f + expf(-(gxz + ghz)));
        float n = tanhf(gxn + r * ghn);
        float* hp = ws_h + (size_t)b * Hn + col;
        *hp = (1.0f - z) * n + z * (*hp);
    }
}

// ================= cooperative single-kernel path =================
__global__ void __launch_bounds__(NTHR, 4)
decode_coop(const float* __restrict__ hidden, const float* __restrict__ emb,
            const float* __restrict__ W_ih, const float* __restrict__ W_hh,
            const float* __restrict__ b_ih, const float* __restrict__ b_hh,
            const float* __restrict__ W_proj, const float* __restrict__ b_proj,
            const int* __restrict__ max_len_p, int* __restrict__ out, void* ws_raw)
{
    cg::grid_group grid = cg::this_grid();
    const int tid = threadIdx.x, bid = blockIdx.x;
    __shared__ SMem sm;

    float* ws_h  = (float*)ws_raw;                         // [B*H]
    float* ws_gh = ws_h + Bn * Hn;                         // [B*3H]
    ull*   slots = (ull*)(ws_gh + Bn * G3H);               // [2][8][B]
    int*   done  = (int*)(slots + 2 * 8 * Bn);             // [2][B]

    const int T = max_len_p[0];

    for (int i = bid * NTHR + tid; i < Bn * Hn / 4; i += NBLK * NTHR)
        ((float4*)ws_h)[i] = ((const float4*)hidden)[i];
    grid.sync();

    phase_b(tid, bid, 1, 0, W_proj, W_hh, b_proj, b_hh, ws_h, ws_gh, slots, &sm);
    grid.sync();

    for (int t = 0; t < T; ++t) {
        phase_a(tid, bid, t, T, emb, W_ih, b_ih, ws_h, ws_gh, slots, done, out, &sm);
        grid.sync();
        phase_b(tid, bid, 0, t, W_proj, W_hh, b_proj, b_hh, ws_h, ws_gh, slots, &sm);
        grid.sync();
    }
    phase_a(tid, bid, T, T, emb, W_ih, b_ih, ws_h, ws_gh, slots, done, out, &sm);
}

// ================= non-cooperative fallback path =================
__global__ void __launch_bounds__(NTHR)
k_init(const float* __restrict__ hidden, float* __restrict__ ws_h) {
    int i = blockIdx.x * NTHR + threadIdx.x;
    if (i < Bn * Hn / 4) ((float4*)ws_h)[i] = ((const float4*)hidden)[i];
}

__global__ void __launch_bounds__(NTHR, 4)
k_b(int first, int t, const int* __restrict__ max_len_p,
    const float* __restrict__ W_proj, const float* __restrict__ W_hh,
    const float* __restrict__ b_proj, const float* __restrict__ b_hh,
    const float* __restrict__ ws_h, float* __restrict__ ws_gh,
    ull* __restrict__ slots)
{
    if (!first && t >= max_len_p[0]) return;
    __shared__ SMem sm;
    phase_b(threadIdx.x, blockIdx.x, first, t, W_proj, W_hh, b_proj, b_hh,
            ws_h, ws_gh, slots, &sm);
}

__global__ void __launch_bounds__(NTHR, 4)
k_a(int t, const int* __restrict__ max_len_p,
    const float* __restrict__ emb, const float* __restrict__ W_ih,
    const float* __restrict__ b_ih,
    float* __restrict__ ws_h, const float* __restrict__ ws_gh,
    ull* __restrict__ slots, int* __restrict__ done, int* __restrict__ out)
{
    int T = max_len_p[0];
    if (t > T) return;
    __shared__ SMem sm;
    phase_a(threadIdx.x, blockIdx.x, t, T, emb, W_ih, b_ih,
            ws_h, ws_gh, slots, done, out, &sm);
}

extern "C" void kernel_launch(void* const* d_in, const int* in_sizes, int n_in,
                              void* d_out, int out_size, void* d_ws, size_t ws_size,
                              hipStream_t stream) {
    const float* hidden = (const float*)d_in[0];
    const float* emb    = (const float*)d_in[1];
    const float* W_ih   = (const float*)d_in[2];
    const float* W_hh   = (const float*)d_in[3];
    const float* b_ih   = (const float*)d_in[4];
    const float* b_hh   = (const float*)d_in[5];
    const float* W_proj = (const float*)d_in[6];
    const float* b_proj = (const float*)d_in[7];
    const int* max_len  = (const int*)d_in[8];
    int* out = (int*)d_out;

    float* ws_h  = (float*)d_ws;
    float* ws_gh = ws_h + Bn * Hn;
    ull*   slots = (ull*)(ws_gh + Bn * G3H);
    int*   done  = (int*)(slots + 2 * 8 * Bn);
    void*  ws    = d_ws;

    void* args[] = {&hidden, &emb, &W_ih, &W_hh, &b_ih, &b_hh,
                    &W_proj, &b_proj, &max_len, &out, &ws};
    hipError_t err = hipLaunchCooperativeKernel((const void*)decode_coop,
                                                dim3(NBLK), dim3(NTHR), args, 0, stream);
    if (err != hipSuccess) {
        (void)hipGetLastError();   // clear sticky error; take deterministic fallback
        hipLaunchKernelGGL(k_init, dim3(4), dim3(NTHR), 0, stream, hidden, ws_h);
        hipLaunchKernelGGL(k_b, dim3(NBLK), dim3(NTHR), 0, stream,
                           1, 0, max_len, W_proj, W_hh, b_proj, b_hh, ws_h, ws_gh, slots);
        for (int t = 0; t <= 64; ++t) {
            hipLaunchKernelGGL(k_a, dim3(NBLK), dim3(NTHR), 0, stream,
                               t, max_len, emb, W_ih, b_ih, ws_h, ws_gh, slots, done, out);
            if (t < 64)
                hipLaunchKernelGGL(k_b, dim3(NBLK), dim3(NTHR), 0, stream,
                                   0, t, max_len, W_proj, W_hh, b_proj, b_hh, ws_h, ws_gh, slots);
        }
    }
}

// Round 4
// 7441.071 us; speedup vs baseline: 1.5617x; 1.2135x over previous
//
#include <hip/hip_runtime.h>
#include <math.h>

#define EOS_TOK 1
#define SOS_TOK 2

#define Bn 32
#define Hn 512
#define En 256
#define Vn 32000
#define G3H 1536                 // 3*H
#define NROWS (Vn + G3H)         // 33536 = 131 * 256
#define NBLK 256                 // 1 block/CU
#define NTHR 1024                // 16 waves/block -> 4 waves/SIMD
#define GROUPS (NTHR / 32)       // 32 row groups
#define VT 4                     // rows per thread per pass
#define RPB (NROWS / NBLK)       // 131 rows per block (exact)
#define GHPB (G3H / NBLK)        // 6 gh rows per block in the pre-pass

typedef unsigned long long ull;

// ---- relaxed agent-scope (device-coherent, no cache-maintenance) accessors ----
template <typename T>
__device__ __forceinline__ T ldA(const T* p) {
    return __hip_atomic_load(p, __ATOMIC_RELAXED, __HIP_MEMORY_SCOPE_AGENT);
}
template <typename T>
__device__ __forceinline__ void stA(T* p, T v) {
    __hip_atomic_store(p, v, __ATOMIC_RELAXED, __HIP_MEMORY_SCOPE_AGENT);
}

// ---- fence-free grid barrier: 32 leaf counters + poller + release word ----
// Monotonic across launches (module globals persist); no reset needed.
struct PadCnt { ull v; ull pad[7]; };
__device__ PadCnt g_leaf[32];     // zero-initialized at module load
__device__ ull    g_release;

__device__ __forceinline__ void grid_barrier(int bid) {
    __syncthreads();
    if (threadIdx.x == 0) {
        __builtin_amdgcn_s_waitcnt(0);   // drain my sc1 stores/atomics to coherence point
        ull my = __hip_atomic_fetch_add(&g_leaf[bid >> 3].v, 1ull,
                                        __ATOMIC_RELAXED, __HIP_MEMORY_SCOPE_AGENT) + 1;
        ull k = (my + 7) >> 3;           // barrier generation
        if (bid == 0) {
            ull need = k << 3;
            for (;;) {
                bool again = false;
                #pragma unroll
                for (int i = 0; i < 32; ++i)
                    again |= (ldA(&g_leaf[i].v) < need);   // 32 independent pipelined loads
                if (!again) break;
                __builtin_amdgcn_s_sleep(1);
            }
            stA(&g_release, k);
        } else {
            while (ldA(&g_release) < k) __builtin_amdgcn_s_sleep(2);
        }
        __asm__ __volatile__("" ::: "memory");
    }
    __syncthreads();
}

// 64 KB exactly. Phase-B h-tile; argmax scratch aliased after h reads complete;
// phase-A scratch aliased (phases separated by barriers).
union SMem {
    float4 h[Bn * (Hn / 4)];                  // 4096 float4, XOR-swizzled
    ull red[GROUPS * Bn];                     // 8 KB, aliases h AFTER all h reads
    struct { int tok[Bn]; float gx[2][3][Bn]; } a;
};

__device__ __forceinline__ unsigned int fkey(float f) {
    // order-preserving fp32 -> u32 (monotone for non-NaN)
    unsigned int b = __float_as_uint(f);
    return (b & 0x80000000u) ? ~b : (b | 0x80000000u);
}

// ---------------- Phase B: logits over V rows + next-step gh rows, partial argmax ----
__device__ __forceinline__ void phase_b(
    int tid, int bid, int first, int t,
    const float* __restrict__ W_proj, const float* __restrict__ W_hh,
    const float* __restrict__ b_proj, const float* __restrict__ b_hh,
    const float* __restrict__ ws_h, float* __restrict__ ws_gh,
    ull* __restrict__ slots, SMem* sm)
{
    // stage h (B x H) into swizzled LDS via agent loads (h was sc1-written by phase A)
    const ull* hsrc = (const ull*)ws_h;
    ull* hdst = (ull*)sm->h;
    for (int j = tid; j < Bn * (Hn / 2); j += NTHR) {   // 8192 ull
        int f4 = j >> 1;
        int b  = f4 >> 7;
        int e4 = f4 & 127;
        hdst[((((b << 7) + (e4 ^ (b & 7)))) << 1) | (j & 1)] = ldA(hsrc + j);
    }
    __syncthreads();

    int rs, re;
    if (first) { rs = Vn + bid * GHPB; re = rs + GHPB; }
    else       { rs = bid * RPB;       re = rs + RPB;  }

    const int g  = tid >> 5;        // row group 0..31
    const int b  = tid & 31;        // batch lane
    const int sw = b & 7;           // swizzle constant
    const float4* hrow = sm->h + (b << 7);
    ull bestPack = 0ull;

    for (int r0 = rs + g * VT; r0 < re; r0 += GROUPS * VT) {
        const int nv = re - r0;     // valid rows this tile (>=1)
        const float* wr[VT];
        #pragma unroll
        for (int i = 0; i < VT; ++i) {
            int r = (i < nv) ? (r0 + i) : r0;   // clamp OOB to a valid row; result unused
            wr[i] = (r < Vn) ? (W_proj + (size_t)r * Hn)
                             : (W_hh   + (size_t)(r - Vn) * Hn);
        }
        float accx[VT], accy[VT];
        #pragma unroll
        for (int i = 0; i < VT; ++i) { accx[i] = 0.f; accy[i] = 0.f; }

        #pragma unroll 2
        for (int e4 = 0; e4 < Hn / 4; ++e4) {
            float4 h4 = hrow[e4 ^ sw];
            #pragma unroll
            for (int i = 0; i < VT; ++i) {
                float4 w4 = *(const float4*)(wr[i] + 4 * e4);
                accx[i] = fmaf(h4.x, w4.x, accx[i]);
                accy[i] = fmaf(h4.y, w4.y, accy[i]);
                accx[i] = fmaf(h4.z, w4.z, accx[i]);
                accy[i] = fmaf(h4.w, w4.w, accy[i]);
            }
        }
        #pragma unroll
        for (int i = 0; i < VT; ++i) {
            if (i < nv) {
                int r = r0 + i;
                float v = accx[i] + accy[i];
                if (r < Vn) {
                    v += b_proj[r];
                    ull pk = ((ull)fkey(v) << 32) | (unsigned int)(~(unsigned int)r);
                    if (pk > bestPack) bestPack = pk;   // ties: smaller r wins via ~r
                } else {
                    stA(&ws_gh[(size_t)b * G3H + (r - Vn)], v + b_hh[r - Vn]);
                }
            }
        }
    }

    if (!first) {
        __syncthreads();                       // all h reads complete before aliasing
        sm->red[(g << 5) + b] = bestPack;
        __syncthreads();
        if (tid < Bn) {
            ull m = sm->red[tid];
            #pragma unroll
            for (int s = 1; s < GROUPS; ++s) {
                ull v = sm->red[(s << 5) + tid];
                if (v > m) m = v;
            }
            if (m != 0ull)
                atomicMax(&slots[((size_t)(t & 1) * 8 + (bid & 7)) * Bn + tid], m);
        }
    }
}

// ---------------- Phase A: token resolve + embed/gx + gate combine + h update -------
__device__ __forceinline__ void phase_a(
    int tid, int bid, int t, int T,
    const float* __restrict__ emb, const float* __restrict__ W_ih,
    const float* __restrict__ b_ih,
    float* __restrict__ ws_h, float* __restrict__ ws_gh,
    ull* __restrict__ slots, int* __restrict__ done,
    int* __restrict__ out, SMem* sm)
{
    if (tid < Bn) {
        int b = tid;
        int tok, dnew;
        if (t == 0) { tok = SOS_TOK; dnew = 0; }
        else {
            const ull* sl = slots + (size_t)((t - 1) & 1) * (8 * Bn);
            ull m = ldA(&sl[b]);
            #pragma unroll
            for (int s = 1; s < 8; ++s) {
                ull v = ldA(&sl[s * Bn + b]);
                if (v > m) m = v;
            }
            int idx = (int)(~(unsigned int)m);
            int dold = ldA(&done[((t - 1) & 1) * Bn + b]);
            tok  = dold ? EOS_TOK : idx;
            dnew = dold | (idx == EOS_TOK);
        }
        sm->a.tok[b] = tok;
        if (bid == 0) {
            stA(&done[(t & 1) * Bn + b], dnew);
            if (t > 0) out[(size_t)(t - 1) * Bn + b] = tok;
            ull* sr = slots + (size_t)(t & 1) * (8 * Bn);   // reset parity (t&1) for B(t)
            #pragma unroll
            for (int s = 0; s < 8; ++s) stA(&sr[s * Bn + b], 0ull);
        }
    }
    __syncthreads();
    if (t >= T) return;          // tail call: resolve only (uniform branch)

    // gx dots: block bid owns columns {bid, bid+256}; 192 dots of length E,
    // 4 threads per dot (64 elems each) -> 768 active threads.
    if (tid < 768) {
        int d    = tid >> 2;     // dot id 0..191
        int q    = tid & 3;      // quarter
        int b    = d & 31;
        int rem  = d >> 5;       // 0..5
        int gate = rem >> 1;
        int ci   = rem & 1;
        int col  = bid + (ci << 8);
        const float* wrow = W_ih + (size_t)(gate * Hn + col) * En + q * (En / 4);
        const float* xrow = emb + (size_t)sm->a.tok[b] * En + q * (En / 4);
        float ax = 0.f, ay = 0.f;
        #pragma unroll
        for (int e4 = 0; e4 < En / 16; ++e4) {     // 16 float4 iters
            float4 w4 = *(const float4*)(wrow + 4 * e4);
            float4 x4 = *(const float4*)(xrow + 4 * e4);
            ax = fmaf(x4.x, w4.x, ax);
            ay = fmaf(x4.y, w4.y, ay);
            ax = fmaf(x4.z, w4.z, ax);
            ay = fmaf(x4.w, w4.w, ay);
        }
        float a = ax + ay;
        a += __shfl_xor(a, 1);
        a += __shfl_xor(a, 2);
        if (q == 0) sm->a.gx[ci][gate][b] = a;
    }
    __syncthreads();

    if (tid < 64) {
        int b   = tid & 31;
        int ci  = tid >> 5;
        int col = bid + (ci << 8);
        float gxr = sm->a.gx[ci][0][b] + b_ih[col];
        float gxz = sm->a.gx[ci][1][b] + b_ih[Hn + col];
        float gxn = sm->a.gx[ci][2][b] + b_ih[2 * Hn + col];
        float* ghrow = ws_gh + (size_t)b * G3H;            // includes b_hh already
        float ghr = ldA(&ghrow[col]);
        float ghz = ldA(&ghrow[Hn + col]);
        float ghn = ldA(&ghrow[2 * Hn + col]);
        float r = 1.0f / (1.0f + expf(-(gxr + ghr)));
        float z = 1.0f / (1.0f + expf(-(gxz + ghz)));
        float n = tanhf(gxn + r * ghn);
        float* hp = ws_h + (size_t)b * Hn + col;
        float hold = ldA(hp);
        stA(hp, (1.0f - z) * n + z * hold);
    }
}

// ================= cooperative single-kernel path (custom fence-free barrier) =======
__global__ void __launch_bounds__(NTHR, 4)
decode_coop(const float* __restrict__ hidden, const float* __restrict__ emb,
            const float* __restrict__ W_ih, const float* __restrict__ W_hh,
            const float* __restrict__ b_ih, const float* __restrict__ b_hh,
            const float* __restrict__ W_proj, const float* __restrict__ b_proj,
            const int* __restrict__ max_len_p, int* __restrict__ out, void* ws_raw)
{
    const int tid = threadIdx.x, bid = blockIdx.x;
    __shared__ SMem sm;

    float* ws_h  = (float*)ws_raw;                         // [B*H]
    float* ws_gh = ws_h + Bn * Hn;                         // [B*3H]
    ull*   slots = (ull*)(ws_gh + Bn * G3H);               // [2][8][B]
    int*   done  = (int*)(slots + 2 * 8 * Bn);             // [2][B]

    const int T = max_len_p[0];

    for (int i = bid * NTHR + tid; i < Bn * Hn / 2; i += NBLK * NTHR)
        stA(((ull*)ws_h) + i, ((const ull*)hidden)[i]);
    grid_barrier(bid);

    phase_b(tid, bid, 1, 0, W_proj, W_hh, b_proj, b_hh, ws_h, ws_gh, slots, &sm);
    grid_barrier(bid);

    for (int t = 0; t < T; ++t) {
        phase_a(tid, bid, t, T, emb, W_ih, b_ih, ws_h, ws_gh, slots, done, out, &sm);
        grid_barrier(bid);
        phase_b(tid, bid, 0, t, W_proj, W_hh, b_proj, b_hh, ws_h, ws_gh, slots, &sm);
        grid_barrier(bid);
    }
    phase_a(tid, bid, T, T, emb, W_ih, b_ih, ws_h, ws_gh, slots, done, out, &sm);
}

// ================= non-cooperative fallback path (kernel-boundary sync) =============
__global__ void __launch_bounds__(NTHR)
k_init(const float* __restrict__ hidden, float* __restrict__ ws_h) {
    int i = blockIdx.x * NTHR + threadIdx.x;
    if (i < Bn * Hn / 4) ((float4*)ws_h)[i] = ((const float4*)hidden)[i];
}

__global__ void __launch_bounds__(NTHR, 4)
k_b(int first, int t, const int* __restrict__ max_len_p,
    const float* __restrict__ W_proj, const float* __restrict__ W_hh,
    const float* __restrict__ b_proj, const float* __restrict__ b_hh,
    const float* __restrict__ ws_h, float* __restrict__ ws_gh,
    ull* __restrict__ slots)
{
    if (!first && t >= max_len_p[0]) return;
    __shared__ SMem sm;
    phase_b(threadIdx.x, blockIdx.x, first, t, W_proj, W_hh, b_proj, b_hh,
            (const float*)ws_h, ws_gh, slots, &sm);
}

__global__ void __launch_bounds__(NTHR, 4)
k_a(int t, const int* __restrict__ max_len_p,
    const float* __restrict__ emb, const float* __restrict__ W_ih,
    const float* __restrict__ b_ih,
    float* __restrict__ ws_h, float* __restrict__ ws_gh,
    ull* __restrict__ slots, int* __restrict__ done, int* __restrict__ out)
{
    int T = max_len_p[0];
    if (t > T) return;
    __shared__ SMem sm;
    phase_a(threadIdx.x, blockIdx.x, t, T, emb, W_ih, b_ih,
            ws_h, ws_gh, slots, done, out, &sm);
}

extern "C" void kernel_launch(void* const* d_in, const int* in_sizes, int n_in,
                              void* d_out, int out_size, void* d_ws, size_t ws_size,
                              hipStream_t stream) {
    const float* hidden = (const float*)d_in[0];
    const float* emb    = (const float*)d_in[1];
    const float* W_ih   = (const float*)d_in[2];
    const float* W_hh   = (const float*)d_in[3];
    const float* b_ih   = (const float*)d_in[4];
    const float* b_hh   = (const float*)d_in[5];
    const float* W_proj = (const float*)d_in[6];
    const float* b_proj = (const float*)d_in[7];
    const int* max_len  = (const int*)d_in[8];
    int* out = (int*)d_out;

    float* ws_h  = (float*)d_ws;
    float* ws_gh = ws_h + Bn * Hn;
    ull*   slots = (ull*)(ws_gh + Bn * G3H);
    int*   done  = (int*)(slots + 2 * 8 * Bn);
    void*  ws    = d_ws;

    void* args[] = {&hidden, &emb, &W_ih, &W_hh, &b_ih, &b_hh,
                    &W_proj, &b_proj, &max_len, &out, &ws};
    hipError_t err = hipLaunchCooperativeKernel((const void*)decode_coop,
                                                dim3(NBLK), dim3(NTHR), args, 0, stream);
    if (err != hipSuccess) {
        (void)hipGetLastError();   // clear sticky error; take deterministic fallback
        hipLaunchKernelGGL(k_init, dim3(4), dim3(NTHR), 0, stream, hidden, ws_h);
        hipLaunchKernelGGL(k_b, dim3(NBLK), dim3(NTHR), 0, stream,
                           1, 0, max_len, W_proj, W_hh, b_proj, b_hh, ws_h, ws_gh, slots);
        for (int t = 0; t <= 64; ++t) {
            hipLaunchKernelGGL(k_a, dim3(NBLK), dim3(NTHR), 0, stream,
                               t, max_len, emb, W_ih, b_ih, ws_h, ws_gh, slots, done, out);
            if (t < 64)
                hipLaunchKernelGGL(k_b, dim3(NBLK), dim3(NTHR), 0, stream,
                                   0, t, max_len, W_proj, W_hh, b_proj, b_hh, ws_h, ws_gh, slots);
        }
    }
}

// Round 5
// 6946.703 us; speedup vs baseline: 1.6729x; 1.0712x over previous
//
#include <hip/hip_runtime.h>
#include <math.h>

#define EOS_TOK 1
#define SOS_TOK 2

#define Bn 32
#define Hn 512
#define En 256
#define Vn 32000
#define G3H 1536                 // 3*H
#define NROWS (Vn + G3H)         // 33536 = 131 * 256
#define NBLK 256                 // 1 block/CU
#define NTHR 1024                // 16 waves/block -> 4 waves/SIMD
#define GROUPS (NTHR / 32)       // 32 row groups
#define VT 4                     // rows per thread per pass
#define PF 4                     // W-load software-pipeline depth (register ring buffer)
#define RPB (NROWS / NBLK)       // 131 rows per block (exact)
#define GHPB (G3H / NBLK)        // 6 gh rows per block in the pre-pass

typedef unsigned long long ull;

// ---- relaxed agent-scope (device-coherent, no cache-maintenance) accessors ----
template <typename T>
__device__ __forceinline__ T ldA(const T* p) {
    return __hip_atomic_load(p, __ATOMIC_RELAXED, __HIP_MEMORY_SCOPE_AGENT);
}
template <typename T>
__device__ __forceinline__ void stA(T* p, T v) {
    __hip_atomic_store(p, v, __ATOMIC_RELAXED, __HIP_MEMORY_SCOPE_AGENT);
}

// ---- fence-free grid barrier: 32 leaf counters + poller + release word ----
// Monotonic across launches (module globals persist); no reset needed.
struct PadCnt { ull v; ull pad[7]; };
__device__ PadCnt g_leaf[32];     // zero-initialized at module load
__device__ ull    g_release;

__device__ __forceinline__ void grid_barrier(int bid) {
    __syncthreads();
    if (threadIdx.x == 0) {
        __builtin_amdgcn_s_waitcnt(0);   // drain my stores/atomics to coherence point
        ull my = __hip_atomic_fetch_add(&g_leaf[bid >> 3].v, 1ull,
                                        __ATOMIC_RELAXED, __HIP_MEMORY_SCOPE_AGENT) + 1;
        ull k = (my + 7) >> 3;           // barrier generation
        if (bid == 0) {
            ull need = k << 3;
            for (;;) {
                bool again = false;
                #pragma unroll
                for (int i = 0; i < 32; ++i)
                    again |= (ldA(&g_leaf[i].v) < need);   // 32 independent pipelined loads
                if (!again) break;
                __builtin_amdgcn_s_sleep(1);
            }
            stA(&g_release, k);
        } else {
            while (ldA(&g_release) < k) __builtin_amdgcn_s_sleep(2);
        }
        __asm__ __volatile__("" ::: "memory");
    }
    __syncthreads();
}

// 64 KB exactly. Phase-B h-tile; argmax scratch aliased after h reads complete;
// phase-A scratch aliased (phases separated by barriers).
union SMem {
    float4 h[Bn * (Hn / 4)];                  // 4096 float4, XOR-swizzled
    ull red[GROUPS * Bn];                     // 8 KB, aliases h AFTER all h reads
    struct { int tok[Bn]; float gx[2][3][Bn]; } a;
};

__device__ __forceinline__ unsigned int fkey(float f) {
    // order-preserving fp32 -> u32 (monotone for non-NaN)
    unsigned int b = __float_as_uint(f);
    return (b & 0x80000000u) ? ~b : (b | 0x80000000u);
}

// ---------------- Phase B: logits over V rows + next-step gh rows, partial argmax ----
__device__ __forceinline__ void phase_b(
    int tid, int bid, int first, int t,
    const float* __restrict__ W_proj, const float* __restrict__ W_hh,
    const float* __restrict__ b_proj, const float* __restrict__ b_hh,
    const float* __restrict__ ws_h, float* __restrict__ ws_gh,
    ull* __restrict__ slots, SMem* sm)
{
    // stage h (B x H) into swizzled LDS via agent loads (h was sc1-written by phase A)
    const ull* hsrc = (const ull*)ws_h;
    ull* hdst = (ull*)sm->h;
    for (int j = tid; j < Bn * (Hn / 2); j += NTHR) {   // 8192 ull
        int f4 = j >> 1;
        int b  = f4 >> 7;
        int e4 = f4 & 127;
        hdst[((((b << 7) + (e4 ^ (b & 7)))) << 1) | (j & 1)] = ldA(hsrc + j);
    }
    __syncthreads();

    int rs, re;
    if (first) { rs = Vn + bid * GHPB; re = rs + GHPB; }
    else       { rs = bid * RPB;       re = rs + RPB;  }

    const int g  = tid >> 5;        // row group 0..31
    const int b  = tid & 31;        // batch lane
    const int sw = b & 7;           // swizzle constant
    const float4* hrow = sm->h + (b << 7);
    ull bestPack = 0ull;

    for (int r0 = rs + g * VT; r0 < re; r0 += GROUPS * VT) {
        const int nv = re - r0;     // valid rows this tile (>=1)
        const float4* pw[VT];
        #pragma unroll
        for (int i = 0; i < VT; ++i) {
            int r = (i < nv) ? (r0 + i) : r0;   // clamp OOB to a valid row; result unused
            pw[i] = (const float4*)((r < Vn) ? (W_proj + (size_t)r * Hn)
                                             : (W_hh   + (size_t)(r - Vn) * Hn));
        }

        // register ring buffer: slots hold W float4s for iterations e4..e4+PF-1
        float4 wb[PF][VT];
        #pragma unroll
        for (int d = 0; d < PF - 1; ++d) {
            #pragma unroll
            for (int i = 0; i < VT; ++i) wb[d][i] = pw[i][d];
        }

        float accx[VT], accy[VT];
        #pragma unroll
        for (int i = 0; i < VT; ++i) { accx[i] = 0.f; accy[i] = 0.f; }

        #pragma unroll 4
        for (int e4 = 0; e4 < Hn / 4; ++e4) {
            const int ls = (e4 + PF - 1) & (PF - 1);        // slot to fill
            const int li = (e4 + PF - 1) & (Hn / 4 - 1);    // wrap: avoids OOB, redundant
            #pragma unroll
            for (int i = 0; i < VT; ++i) wb[ls][i] = pw[i][li];   // issue prefetch first

            float4 h4 = hrow[e4 ^ sw];
            const int cs = e4 & (PF - 1);                   // slot to consume (loaded 3 iters ago)
            #pragma unroll
            for (int i = 0; i < VT; ++i) {
                accx[i] = fmaf(h4.x, wb[cs][i].x, accx[i]);
                accy[i] = fmaf(h4.y, wb[cs][i].y, accy[i]);
                accx[i] = fmaf(h4.z, wb[cs][i].z, accx[i]);
                accy[i] = fmaf(h4.w, wb[cs][i].w, accy[i]);
            }
        }
        #pragma unroll
        for (int i = 0; i < VT; ++i) {
            if (i < nv) {
                int r = r0 + i;
                float v = accx[i] + accy[i];
                if (r < Vn) {
                    v += b_proj[r];
                    ull pk = ((ull)fkey(v) << 32) | (unsigned int)(~(unsigned int)r);
                    if (pk > bestPack) bestPack = pk;   // ties: smaller r wins via ~r
                } else {
                    stA(&ws_gh[(size_t)b * G3H + (r - Vn)], v + b_hh[r - Vn]);
                }
            }
        }
    }

    if (!first) {
        __syncthreads();                       // all h reads complete before aliasing
        sm->red[(g << 5) + b] = bestPack;
        __syncthreads();
        if (tid < Bn) {
            ull m = sm->red[tid];
            #pragma unroll
            for (int s = 1; s < GROUPS; ++s) {
                ull v = sm->red[(s << 5) + tid];
                if (v > m) m = v;
            }
            if (m != 0ull)
                atomicMax(&slots[((size_t)(t & 1) * 8 + (bid & 7)) * Bn + tid], m);
        }
    }
}

// ---------------- Phase A: token resolve + embed/gx + gate combine + h update -------
__device__ __forceinline__ void phase_a(
    int tid, int bid, int t, int T,
    const float* __restrict__ emb, const float* __restrict__ W_ih,
    const float* __restrict__ b_ih,
    float* __restrict__ ws_h, float* __restrict__ ws_gh,
    ull* __restrict__ slots, int* __restrict__ done,
    int* __restrict__ out, SMem* sm)
{
    if (tid < Bn) {
        int b = tid;
        int tok, dnew;
        if (t == 0) { tok = SOS_TOK; dnew = 0; }
        else {
            const ull* sl = slots + (size_t)((t - 1) & 1) * (8 * Bn);
            ull m = ldA(&sl[b]);
            #pragma unroll
            for (int s = 1; s < 8; ++s) {
                ull v = ldA(&sl[s * Bn + b]);
                if (v > m) m = v;
            }
            int idx = (int)(~(unsigned int)m);
            int dold = ldA(&done[((t - 1) & 1) * Bn + b]);
            tok  = dold ? EOS_TOK : idx;
            dnew = dold | (idx == EOS_TOK);
        }
        sm->a.tok[b] = tok;
        if (bid == 0) {
            stA(&done[(t & 1) * Bn + b], dnew);
            if (t > 0) out[(size_t)(t - 1) * Bn + b] = tok;
            ull* sr = slots + (size_t)(t & 1) * (8 * Bn);   // reset parity (t&1) for B(t)
            #pragma unroll
            for (int s = 0; s < 8; ++s) stA(&sr[s * Bn + b], 0ull);
        }
    }
    __syncthreads();
    if (t >= T) return;          // tail call: resolve only (uniform branch)

    // gx dots: block bid owns columns {bid, bid+256}; 192 dots of length E,
    // 4 threads per dot (64 elems each) -> 768 active threads.
    if (tid < 768) {
        int d    = tid >> 2;     // dot id 0..191
        int q    = tid & 3;      // quarter
        int b    = d & 31;
        int rem  = d >> 5;       // 0..5
        int gate = rem >> 1;
        int ci   = rem & 1;
        int col  = bid + (ci << 8);
        const float* wrow = W_ih + (size_t)(gate * Hn + col) * En + q * (En / 4);
        const float* xrow = emb + (size_t)sm->a.tok[b] * En + q * (En / 4);
        float ax = 0.f, ay = 0.f;
        #pragma unroll
        for (int e4 = 0; e4 < En / 16; ++e4) {     // 16 float4 iters
            float4 w4 = *(const float4*)(wrow + 4 * e4);
            float4 x4 = *(const float4*)(xrow + 4 * e4);
            ax = fmaf(x4.x, w4.x, ax);
            ay = fmaf(x4.y, w4.y, ay);
            ax = fmaf(x4.z, w4.z, ax);
            ay = fmaf(x4.w, w4.w, ay);
        }
        float a = ax + ay;
        a += __shfl_xor(a, 1);
        a += __shfl_xor(a, 2);
        if (q == 0) sm->a.gx[ci][gate][b] = a;
    }
    __syncthreads();

    if (tid < 64) {
        int b   = tid & 31;
        int ci  = tid >> 5;
        int col = bid + (ci << 8);
        float gxr = sm->a.gx[ci][0][b] + b_ih[col];
        float gxz = sm->a.gx[ci][1][b] + b_ih[Hn + col];
        float gxn = sm->a.gx[ci][2][b] + b_ih[2 * Hn + col];
        float* ghrow = ws_gh + (size_t)b * G3H;            // includes b_hh already
        float ghr = ldA(&ghrow[col]);
        float ghz = ldA(&ghrow[Hn + col]);
        float ghn = ldA(&ghrow[2 * Hn + col]);
        float r = 1.0f / (1.0f + expf(-(gxr + ghr)));
        float z = 1.0f / (1.0f + expf(-(gxz + ghz)));
        float n = tanhf(gxn + r * ghn);
        float* hp = ws_h + (size_t)b * Hn + col;
        float hold = ldA(hp);
        stA(hp, (1.0f - z) * n + z * hold);
    }
}

// ================= cooperative single-kernel path (custom fence-free barrier) =======
__global__ void __launch_bounds__(NTHR, 4)
decode_coop(const float* __restrict__ hidden, const float* __restrict__ emb,
            const float* __restrict__ W_ih, const float* __restrict__ W_hh,
            const float* __restrict__ b_ih, const float* __restrict__ b_hh,
            const float* __restrict__ W_proj, const float* __restrict__ b_proj,
            const int* __restrict__ max_len_p, int* __restrict__ out, void* ws_raw)
{
    const int tid = threadIdx.x, bid = blockIdx.x;
    __shared__ SMem sm;

    float* ws_h  = (float*)ws_raw;                         // [B*H]
    float* ws_gh = ws_h + Bn * Hn;                         // [B*3H]
    ull*   slots = (ull*)(ws_gh + Bn * G3H);               // [2][8][B]
    int*   done  = (int*)(slots + 2 * 8 * Bn);             // [2][B]

    const int T = max_len_p[0];

    for (int i = bid * NTHR + tid; i < Bn * Hn / 2; i += NBLK * NTHR)
        stA(((ull*)ws_h) + i, ((const ull*)hidden)[i]);
    grid_barrier(bid);

    phase_b(tid, bid, 1, 0, W_proj, W_hh, b_proj, b_hh, ws_h, ws_gh, slots, &sm);
    grid_barrier(bid);

    for (int t = 0; t < T; ++t) {
        phase_a(tid, bid, t, T, emb, W_ih, b_ih, ws_h, ws_gh, slots, done, out, &sm);
        grid_barrier(bid);
        phase_b(tid, bid, 0, t, W_proj, W_hh, b_proj, b_hh, ws_h, ws_gh, slots, &sm);
        grid_barrier(bid);
    }
    phase_a(tid, bid, T, T, emb, W_ih, b_ih, ws_h, ws_gh, slots, done, out, &sm);
}

// ================= non-cooperative fallback path (kernel-boundary sync) =============
__global__ void __launch_bounds__(NTHR)
k_init(const float* __restrict__ hidden, float* __restrict__ ws_h) {
    int i = blockIdx.x * NTHR + threadIdx.x;
    if (i < Bn * Hn / 4) ((float4*)ws_h)[i] = ((const float4*)hidden)[i];
}

__global__ void __launch_bounds__(NTHR, 4)
k_b(int first, int t, const int* __restrict__ max_len_p,
    const float* __restrict__ W_proj, const float* __restrict__ W_hh,
    const float* __restrict__ b_proj, const float* __restrict__ b_hh,
    const float* __restrict__ ws_h, float* __restrict__ ws_gh,
    ull* __restrict__ slots)
{
    if (!first && t >= max_len_p[0]) return;
    __shared__ SMem sm;
    phase_b(threadIdx.x, blockIdx.x, first, t, W_proj, W_hh, b_proj, b_hh,
            (const float*)ws_h, ws_gh, slots, &sm);
}

__global__ void __launch_bounds__(NTHR, 4)
k_a(int t, const int* __restrict__ max_len_p,
    const float* __restrict__ emb, const float* __restrict__ W_ih,
    const float* __restrict__ b_ih,
    float* __restrict__ ws_h, float* __restrict__ ws_gh,
    ull* __restrict__ slots, int* __restrict__ done, int* __restrict__ out)
{
    int T = max_len_p[0];
    if (t > T) return;
    __shared__ SMem sm;
    phase_a(threadIdx.x, blockIdx.x, t, T, emb, W_ih, b_ih,
            ws_h, ws_gh, slots, done, out, &sm);
}

extern "C" void kernel_launch(void* const* d_in, const int* in_sizes, int n_in,
                              void* d_out, int out_size, void* d_ws, size_t ws_size,
                              hipStream_t stream) {
    const float* hidden = (const float*)d_in[0];
    const float* emb    = (const float*)d_in[1];
    const float* W_ih   = (const float*)d_in[2];
    const float* W_hh   = (const float*)d_in[3];
    const float* b_ih   = (const float*)d_in[4];
    const float* b_hh   = (const float*)d_in[5];
    const float* W_proj = (const float*)d_in[6];
    const float* b_proj = (const float*)d_in[7];
    const int* max_len  = (const int*)d_in[8];
    int* out = (int*)d_out;

    float* ws_h  = (float*)d_ws;
    float* ws_gh = ws_h + Bn * Hn;
    ull*   slots = (ull*)(ws_gh + Bn * G3H);
    int*   done  = (int*)(slots + 2 * 8 * Bn);
    void*  ws    = d_ws;

    void* args[] = {&hidden, &emb, &W_ih, &W_hh, &b_ih, &b_hh,
                    &W_proj, &b_proj, &max_len, &out, &ws};
    hipError_t err = hipLaunchCooperativeKernel((const void*)decode_coop,
                                                dim3(NBLK), dim3(NTHR), args, 0, stream);
    if (err != hipSuccess) {
        (void)hipGetLastError();   // clear sticky error; take deterministic fallback
        hipLaunchKernelGGL(k_init, dim3(4), dim3(NTHR), 0, stream, hidden, ws_h);
        hipLaunchKernelGGL(k_b, dim3(NBLK), dim3(NTHR), 0, stream,
                           1, 0, max_len, W_proj, W_hh, b_proj, b_hh, ws_h, ws_gh, slots);
        for (int t = 0; t <= 64; ++t) {
            hipLaunchKernelGGL(k_a, dim3(NBLK), dim3(NTHR), 0, stream,
                               t, max_len, emb, W_ih, b_ih, ws_h, ws_gh, slots, done, out);
            if (t < 64)
                hipLaunchKernelGGL(k_b, dim3(NBLK), dim3(NTHR), 0, stream,
                                   0, t, max_len, W_proj, W_hh, b_proj, b_hh, ws_h, ws_gh, slots);
        }
    }
}

// Round 6
// 6776.486 us; speedup vs baseline: 1.7149x; 1.0251x over previous
//
#include <hip/hip_runtime.h>
#include <math.h>

#define EOS_TOK 1
#define SOS_TOK 2

#define Bn 32
#define Hn 512
#define En 256
#define Vn 32000
#define G3H 1536                 // 3*H
#define NROWS (Vn + G3H)         // 33536 = 131 * 256
#define NBLK 256                 // 1 block/CU
#define NTHR 1024                // 16 waves: 14 consumer + 2 prefetch
#define GROUPS 32                // reduction groups (all waves)
#define CGROUPS 28               // consumer row groups (waves 0..13)
#define VT 4                     // rows per consumer thread per pass
#define PF 4                     // W-load ring depth (kept from R5)
#define RPB (NROWS / NBLK)       // 131 rows per block (exact)
#define GHPB (G3H / NBLK)        // 6 gh rows per block in the pre-pass

typedef unsigned long long ull;

// ---- relaxed agent-scope (device-coherent, no cache-maintenance) accessors ----
template <typename T>
__device__ __forceinline__ T ldA(const T* p) {
    return __hip_atomic_load(p, __ATOMIC_RELAXED, __HIP_MEMORY_SCOPE_AGENT);
}
template <typename T>
__device__ __forceinline__ void stA(T* p, T v) {
    __hip_atomic_store(p, v, __ATOMIC_RELAXED, __HIP_MEMORY_SCOPE_AGENT);
}

// ---- fence-free grid barrier: 32 leaf counters + poller + release word ----
struct PadCnt { ull v; ull pad[7]; };
__device__ PadCnt g_leaf[32];     // zero-initialized at module load; monotonic
__device__ ull    g_release;

__device__ __forceinline__ void grid_barrier(int bid) {
    __syncthreads();
    if (threadIdx.x == 0) {
        __builtin_amdgcn_s_waitcnt(0);   // drain my stores/atomics to coherence point
        ull my = __hip_atomic_fetch_add(&g_leaf[bid >> 3].v, 1ull,
                                        __ATOMIC_RELAXED, __HIP_MEMORY_SCOPE_AGENT) + 1;
        ull k = (my + 7) >> 3;           // barrier generation
        if (bid == 0) {
            ull need = k << 3;
            for (;;) {
                bool again = false;
                #pragma unroll
                for (int i = 0; i < 32; ++i)
                    again |= (ldA(&g_leaf[i].v) < need);
                if (!again) break;
                __builtin_amdgcn_s_sleep(1);
            }
            stA(&g_release, k);
        } else {
            while (ldA(&g_release) < k) __builtin_amdgcn_s_sleep(2);
        }
        __asm__ __volatile__("" ::: "memory");
    }
    __syncthreads();
}

// 64 KB exactly.
union SMem {
    float4 h[Bn * (Hn / 4)];                  // 4096 float4, XOR-swizzled
    ull red[GROUPS * Bn];                     // 8 KB, aliases h AFTER all h reads
    struct { int tok[Bn]; float gx[2][3][Bn]; } a;
};

__device__ __forceinline__ unsigned int fkey(float f) {
    unsigned int b = __float_as_uint(f);
    return (b & 0x80000000u) ? ~b : (b | 0x80000000u);
}

// ---------------- Phase B: logits + next-step gh, partial argmax, L2 prefetch ------
__device__ __forceinline__ void phase_b(
    int tid, int bid, int first, int t,
    const float* __restrict__ W_proj, const float* __restrict__ W_hh,
    const float* __restrict__ b_proj, const float* __restrict__ b_hh,
    const float* __restrict__ ws_h, float* __restrict__ ws_gh,
    ull* __restrict__ slots, SMem* sm)
{
    // stage h (B x H) into swizzled LDS (h was agent-written by phase A)
    const ull* hsrc = (const ull*)ws_h;
    ull* hdst = (ull*)sm->h;
    for (int j = tid; j < Bn * (Hn / 2); j += NTHR) {   // 8192 ull
        int f4 = j >> 1;
        int b  = f4 >> 7;
        int e4 = f4 & 127;
        hdst[((((b << 7) + (e4 ^ (b & 7)))) << 1) | (j & 1)] = ldA(hsrc + j);
    }
    __syncthreads();

    int rs, re;
    if (first) { rs = Vn + bid * GHPB; re = rs + GHPB; }
    else       { rs = bid * RPB;       re = rs + RPB;  }

    const int g = tid >> 5;         // group 0..31 (28..31 = prefetch waves)
    const int b = tid & 31;
    ull bestPack = 0ull;

    if (tid < CGROUPS * 32) {
        // ---------------- consumer: fp32 GEMV rows from global (L2-warmed) --------
        const int sw = b & 7;
        const float4* hrow = sm->h + (b << 7);

        for (int r0 = rs + g * VT; r0 < re; r0 += CGROUPS * VT) {
            const int nv = re - r0;
            const float4* pw[VT];
            #pragma unroll
            for (int i = 0; i < VT; ++i) {
                int r = (i < nv) ? (r0 + i) : r0;
                pw[i] = (const float4*)((r < Vn) ? (W_proj + (size_t)r * Hn)
                                                 : (W_hh   + (size_t)(r - Vn) * Hn));
            }

            float4 wb[PF][VT];
            #pragma unroll
            for (int d = 0; d < PF - 1; ++d) {
                #pragma unroll
                for (int i = 0; i < VT; ++i) wb[d][i] = pw[i][d];
            }

            float accx[VT], accy[VT];
            #pragma unroll
            for (int i = 0; i < VT; ++i) { accx[i] = 0.f; accy[i] = 0.f; }

            #pragma unroll 4
            for (int e4 = 0; e4 < Hn / 4; ++e4) {
                const int ls = (e4 + PF - 1) & (PF - 1);
                const int li = (e4 + PF - 1) & (Hn / 4 - 1);
                #pragma unroll
                for (int i = 0; i < VT; ++i) wb[ls][i] = pw[i][li];

                float4 h4 = hrow[e4 ^ sw];
                const int cs = e4 & (PF - 1);
                #pragma unroll
                for (int i = 0; i < VT; ++i) {
                    accx[i] = fmaf(h4.x, wb[cs][i].x, accx[i]);
                    accy[i] = fmaf(h4.y, wb[cs][i].y, accy[i]);
                    accx[i] = fmaf(h4.z, wb[cs][i].z, accx[i]);
                    accy[i] = fmaf(h4.w, wb[cs][i].w, accy[i]);
                }
            }
            #pragma unroll
            for (int i = 0; i < VT; ++i) {
                if (i < nv) {
                    int r = r0 + i;
                    float v = accx[i] + accy[i];
                    if (r < Vn) {
                        v += b_proj[r];
                        ull pk = ((ull)fkey(v) << 32) | (unsigned int)(~(unsigned int)r);
                        if (pk > bestPack) bestPack = pk;
                    } else {
                        stA(&ws_gh[(size_t)b * G3H + (r - Vn)], v + b_hh[r - Vn]);
                    }
                }
            }
        }
    } else if (!first) {
        // ---------------- prefetch waves: pull all 131 rows' lines into local L2 --
        // K-ordered walk: one 4B touch per 128B line, 131 rows x 16 windows.
        const int p = tid - CGROUPS * 32;    // 0..127
        float pacc = 0.f;
        int row = p, win = 0;
        if (row >= RPB) { row -= RPB; ++win; }   // p in [0,127] < 131: no-op, safe
        #pragma unroll
        for (int it = 0; it < 17; ++it) {
            if (win < 16) {
                int rg = rs + row;
                const float* rb = (rg < Vn) ? (W_proj + (size_t)rg * Hn)
                                            : (W_hh   + (size_t)(rg - Vn) * Hn);
                pacc += rb[win << 5];            // touches the 128B line -> L2 fill
            }
            row += 128;
            if (row >= RPB) { row -= RPB; ++win; }
        }
        // fold into reduction as a provably-neutral value; defeats DCE.
        bestPack = (__float_as_uint(pacc) == 0x7F800001u) ? 1ull : 0ull;
    }

    if (!first) {
        __syncthreads();                       // all h reads complete before aliasing
        sm->red[(g << 5) + b] = bestPack;
        __syncthreads();
        if (tid < Bn) {
            ull m = sm->red[tid];
            #pragma unroll
            for (int s = 1; s < GROUPS; ++s) {
                ull v = sm->red[(s << 5) + tid];
                if (v > m) m = v;
            }
            if (m != 0ull)
                atomicMax(&slots[((size_t)(t & 1) * 8 + (bid & 7)) * Bn + tid], m);
        }
    }
}

// ---------------- Phase A: token resolve + embed/gx + gate combine + h update -------
__device__ __forceinline__ void phase_a(
    int tid, int bid, int t, int T,
    const float* __restrict__ emb, const float* __restrict__ W_ih,
    const float* __restrict__ b_ih,
    float* __restrict__ ws_h, float* __restrict__ ws_gh,
    ull* __restrict__ slots, int* __restrict__ done,
    int* __restrict__ out, SMem* sm)
{
    if (tid < Bn) {
        int b = tid;
        int tok, dnew;
        if (t == 0) { tok = SOS_TOK; dnew = 0; }
        else {
            const ull* sl = slots + (size_t)((t - 1) & 1) * (8 * Bn);
            ull m = ldA(&sl[b]);
            #pragma unroll
            for (int s = 1; s < 8; ++s) {
                ull v = ldA(&sl[s * Bn + b]);
                if (v > m) m = v;
            }
            int idx = (int)(~(unsigned int)m);
            int dold = ldA(&done[((t - 1) & 1) * Bn + b]);
            tok  = dold ? EOS_TOK : idx;
            dnew = dold | (idx == EOS_TOK);
        }
        sm->a.tok[b] = tok;
        if (bid == 0) {
            stA(&done[(t & 1) * Bn + b], dnew);
            if (t > 0) out[(size_t)(t - 1) * Bn + b] = tok;
            ull* sr = slots + (size_t)(t & 1) * (8 * Bn);
            #pragma unroll
            for (int s = 0; s < 8; ++s) stA(&sr[s * Bn + b], 0ull);
        }
    }
    __syncthreads();
    if (t >= T) return;

    if (tid < 768) {
        int d    = tid >> 2;
        int q    = tid & 3;
        int b    = d & 31;
        int rem  = d >> 5;
        int gate = rem >> 1;
        int ci   = rem & 1;
        int col  = bid + (ci << 8);
        const float* wrow = W_ih + (size_t)(gate * Hn + col) * En + q * (En / 4);
        const float* xrow = emb + (size_t)sm->a.tok[b] * En + q * (En / 4);
        float ax = 0.f, ay = 0.f;
        #pragma unroll
        for (int e4 = 0; e4 < En / 16; ++e4) {
            float4 w4 = *(const float4*)(wrow + 4 * e4);
            float4 x4 = *(const float4*)(xrow + 4 * e4);
            ax = fmaf(x4.x, w4.x, ax);
            ay = fmaf(x4.y, w4.y, ay);
            ax = fmaf(x4.z, w4.z, ax);
            ay = fmaf(x4.w, w4.w, ay);
        }
        float a = ax + ay;
        a += __shfl_xor(a, 1);
        a += __shfl_xor(a, 2);
        if (q == 0) sm->a.gx[ci][gate][b] = a;
    }
    __syncthreads();

    if (tid < 64) {
        int b   = tid & 31;
        int ci  = tid >> 5;
        int col = bid + (ci << 8);
        float gxr = sm->a.gx[ci][0][b] + b_ih[col];
        float gxz = sm->a.gx[ci][1][b] + b_ih[Hn + col];
        float gxn = sm->a.gx[ci][2][b] + b_ih[2 * Hn + col];
        float* ghrow = ws_gh + (size_t)b * G3H;            // includes b_hh already
        float ghr = ldA(&ghrow[col]);
        float ghz = ldA(&ghrow[Hn + col]);
        float ghn = ldA(&ghrow[2 * Hn + col]);
        float r = 1.0f / (1.0f + expf(-(gxr + ghr)));
        float z = 1.0f / (1.0f + expf(-(gxz + ghz)));
        float n = tanhf(gxn + r * ghn);
        float* hp = ws_h + (size_t)b * Hn + col;
        float hold = ldA(hp);
        stA(hp, (1.0f - z) * n + z * hold);
    }
}

// ================= cooperative single-kernel path =================
__global__ void __launch_bounds__(NTHR, 4)
decode_coop(const float* __restrict__ hidden, const float* __restrict__ emb,
            const float* __restrict__ W_ih, const float* __restrict__ W_hh,
            const float* __restrict__ b_ih, const float* __restrict__ b_hh,
            const float* __restrict__ W_proj, const float* __restrict__ b_proj,
            const int* __restrict__ max_len_p, int* __restrict__ out, void* ws_raw)
{
    const int tid = threadIdx.x, bid = blockIdx.x;
    __shared__ SMem sm;

    float* ws_h  = (float*)ws_raw;
    float* ws_gh = ws_h + Bn * Hn;
    ull*   slots = (ull*)(ws_gh + Bn * G3H);
    int*   done  = (int*)(slots + 2 * 8 * Bn);

    const int T = max_len_p[0];

    for (int i = bid * NTHR + tid; i < Bn * Hn / 2; i += NBLK * NTHR)
        stA(((ull*)ws_h) + i, ((const ull*)hidden)[i]);
    grid_barrier(bid);

    phase_b(tid, bid, 1, 0, W_proj, W_hh, b_proj, b_hh, ws_h, ws_gh, slots, &sm);
    grid_barrier(bid);

    for (int t = 0; t < T; ++t) {
        phase_a(tid, bid, t, T, emb, W_ih, b_ih, ws_h, ws_gh, slots, done, out, &sm);
        grid_barrier(bid);
        phase_b(tid, bid, 0, t, W_proj, W_hh, b_proj, b_hh, ws_h, ws_gh, slots, &sm);
        grid_barrier(bid);
    }
    phase_a(tid, bid, T, T, emb, W_ih, b_ih, ws_h, ws_gh, slots, done, out, &sm);
}

// ================= non-cooperative fallback path =================
__global__ void __launch_bounds__(NTHR)
k_init(const float* __restrict__ hidden, float* __restrict__ ws_h) {
    int i = blockIdx.x * NTHR + threadIdx.x;
    if (i < Bn * Hn / 4) ((float4*)ws_h)[i] = ((const float4*)hidden)[i];
}

__global__ void __launch_bounds__(NTHR, 4)
k_b(int first, int t, const int* __restrict__ max_len_p,
    const float* __restrict__ W_proj, const float* __restrict__ W_hh,
    const float* __restrict__ b_proj, const float* __restrict__ b_hh,
    const float* __restrict__ ws_h, float* __restrict__ ws_gh,
    ull* __restrict__ slots)
{
    if (!first && t >= max_len_p[0]) return;
    __shared__ SMem sm;
    phase_b(threadIdx.x, blockIdx.x, first, t, W_proj, W_hh, b_proj, b_hh,
            (const float*)ws_h, ws_gh, slots, &sm);
}

__global__ void __launch_bounds__(NTHR, 4)
k_a(int t, const int* __restrict__ max_len_p,
    const float* __restrict__ emb, const float* __restrict__ W_ih,
    const float* __restrict__ b_ih,
    float* __restrict__ ws_h, float* __restrict__ ws_gh,
    ull* __restrict__ slots, int* __restrict__ done, int* __restrict__ out)
{
    int T = max_len_p[0];
    if (t > T) return;
    __shared__ SMem sm;
    phase_a(threadIdx.x, blockIdx.x, t, T, emb, W_ih, b_ih,
            ws_h, ws_gh, slots, done, out, &sm);
}

extern "C" void kernel_launch(void* const* d_in, const int* in_sizes, int n_in,
                              void* d_out, int out_size, void* d_ws, size_t ws_size,
                              hipStream_t stream) {
    const float* hidden = (const float*)d_in[0];
    const float* emb    = (const float*)d_in[1];
    const float* W_ih   = (const float*)d_in[2];
    const float* W_hh   = (const float*)d_in[3];
    const float* b_ih   = (const float*)d_in[4];
    const float* b_hh   = (const float*)d_in[5];
    const float* W_proj = (const float*)d_in[6];
    const float* b_proj = (const float*)d_in[7];
    const int* max_len  = (const int*)d_in[8];
    int* out = (int*)d_out;

    float* ws_h  = (float*)d_ws;
    float* ws_gh = ws_h + Bn * Hn;
    ull*   slots = (ull*)(ws_gh + Bn * G3H);
    int*   done  = (int*)(slots + 2 * 8 * Bn);
    void*  ws    = d_ws;

    void* args[] = {&hidden, &emb, &W_ih, &W_hh, &b_ih, &b_hh,
                    &W_proj, &b_proj, &max_len, &out, &ws};
    hipError_t err = hipLaunchCooperativeKernel((const void*)decode_coop,
                                                dim3(NBLK), dim3(NTHR), args, 0, stream);
    if (err != hipSuccess) {
        (void)hipGetLastError();
        hipLaunchKernelGGL(k_init, dim3(4), dim3(NTHR), 0, stream, hidden, ws_h);
        hipLaunchKernelGGL(k_b, dim3(NBLK), dim3(NTHR), 0, stream,
                           1, 0, max_len, W_proj, W_hh, b_proj, b_hh, ws_h, ws_gh, slots);
        for (int t = 0; t <= 64; ++t) {
            hipLaunchKernelGGL(k_a, dim3(NBLK), dim3(NTHR), 0, stream,
                               t, max_len, emb, W_ih, b_ih, ws_h, ws_gh, slots, done, out);
            if (t < 64)
                hipLaunchKernelGGL(k_b, dim3(NBLK), dim3(NTHR), 0, stream,
                                   0, t, max_len, W_proj, W_hh, b_proj, b_hh, ws_h, ws_gh, slots);
        }
    }
}